// Round 1
// baseline (295.433 us; speedup 1.0000x reference)
//
#include <hip/hip_runtime.h>

// PoseCost: SE(3) log-map pose error over N = B*H poses.
// in:  pos [N,3] f32, rot [N,9] f32 (row-major 3x3), goal_pos [3], goal_rot [9], vec_weight [6]
// out: cost [N], rot_err [N], pos_err [N], v [N,3], omega [N,3]  (concat flat, f32)

#define BLOCK 256

__global__ __launch_bounds__(BLOCK) void pose_cost_kernel(
    const float* __restrict__ pos,
    const float* __restrict__ rot,
    const float* __restrict__ gpos,
    const float* __restrict__ grot,
    const float* __restrict__ wvec,
    float* __restrict__ out,
    int N)
{
    __shared__ float sR[BLOCK * 9];   // staging: R tiles in, then reused for v/omega out
    __shared__ float sP[BLOCK * 3];

    const int t = threadIdx.x;
    const int base = blockIdx.x * BLOCK;
    const bool fullBlock = (base + BLOCK) <= N;

    // ---- Stage inputs: fully coalesced linear loads into LDS ----
    {
        const float* rsrc = rot + (size_t)base * 9;
        const float* psrc = pos + (size_t)base * 3;
        if (fullBlock) {
            #pragma unroll
            for (int k = 0; k < 9; ++k) sR[k * BLOCK + t] = rsrc[k * BLOCK + t];
            #pragma unroll
            for (int k = 0; k < 3; ++k) sP[k * BLOCK + t] = psrc[k * BLOCK + t];
        } else {
            int rem = N - base;                 // < BLOCK
            #pragma unroll
            for (int k = 0; k < 9; ++k) {
                int i = k * BLOCK + t;
                if (i < rem * 9) sR[i] = rsrc[i];
            }
            #pragma unroll
            for (int k = 0; k < 3; ++k) {
                int i = k * BLOCK + t;
                if (i < rem * 3) sP[i] = psrc[i];
            }
        }
    }

    // uniform (wave-invariant) goal / weight data -> scalar loads
    float G[9], g0, g1, g2, w[6];
    #pragma unroll
    for (int k = 0; k < 9; ++k) G[k] = grot[k];
    g0 = gpos[0]; g1 = gpos[1]; g2 = gpos[2];
    #pragma unroll
    for (int k = 0; k < 6; ++k) w[k] = wvec[k];

    __syncthreads();

    const int idx = base + t;
    const bool active = idx < N;

    float cost = 0.f, re = 0.f, pe = 0.f;
    float v0 = 0.f, v1 = 0.f, v2 = 0.f, o0 = 0.f, o1 = 0.f, o2 = 0.f;

    if (active) {
        float R[9];
        #pragma unroll
        for (int k = 0; k < 9; ++k) R[k] = sR[t * 9 + k];
        const float p0 = sP[t * 3 + 0];
        const float p1 = sP[t * 3 + 1];
        const float p2 = sP[t * 3 + 2];

        // d = goal_pos - p ;  t_ge = R^T d
        const float d0 = g0 - p0, d1 = g1 - p1, d2 = g2 - p2;
        const float tq0 = R[0] * d0 + R[3] * d1 + R[6] * d2;
        const float tq1 = R[1] * d0 + R[4] * d1 + R[7] * d2;
        const float tq2 = R[2] * d0 + R[5] * d1 + R[8] * d2;

        // M = R^T * G   (M[i][j] = sum_k R[k][i] * G[k][j])
        float M[9];
        #pragma unroll
        for (int i = 0; i < 3; ++i) {
            #pragma unroll
            for (int j = 0; j < 3; ++j) {
                M[i * 3 + j] = R[0 + i] * G[0 + j] + R[3 + i] * G[3 + j] + R[6 + i] * G[6 + j];
            }
        }

        const float tr = M[0] + M[4] + M[8];
        float cos_t = (tr - 1.0f) * 0.5f;
        cos_t = fminf(fmaxf(cos_t, -1.0f + 1e-7f), 1.0f - 1e-7f);
        const float theta = acosf(cos_t);
        const float sin_t = sinf(theta);

        // vee(M - M^T)/2
        const float wv0 = 0.5f * (M[7] - M[5]);
        const float wv1 = 0.5f * (M[2] - M[6]);
        const float wv2 = 0.5f * (M[3] - M[1]);

        const bool small = theta < 1e-4f;
        const float th2 = theta * theta;
        const float scale = small ? (1.0f + th2 * (1.0f / 6.0f)) : (theta / sin_t);
        o0 = scale * wv0; o1 = scale * wv1; o2 = scale * wv2;

        const float theta2 = small ? 1.0f : th2;
        const float A = small ? (1.0f / 12.0f)
                              : (1.0f - (theta * sin_t) / (2.0f * (1.0f - cos_t))) / theta2;

        // v = Vinv t = t - 0.5*(omega x t) + A*(omega*(omega.t) - |omega|^2 * t)
        const float cx0 = o1 * tq2 - o2 * tq1;
        const float cx1 = o2 * tq0 - o0 * tq2;
        const float cx2 = o0 * tq1 - o1 * tq0;
        const float odt = o0 * tq0 + o1 * tq1 + o2 * tq2;
        const float on2 = o0 * o0 + o1 * o1 + o2 * o2;
        v0 = tq0 - 0.5f * cx0 + A * (o0 * odt - on2 * tq0);
        v1 = tq1 - 0.5f * cx1 + A * (o1 * odt - on2 * tq1);
        v2 = tq2 - 0.5f * cx2 + A * (o2 * odt - on2 * tq2);

        const float we0 = w[0] * o0, we1 = w[1] * o1, we2 = w[2] * o2;
        const float wp0 = w[3] * v0, wp1 = w[4] * v1, wp2 = w[5] * v2;
        re = we0 * we0 + we1 * we1 + we2 * we2;
        pe = wp0 * wp0 + wp1 * wp1 + wp2 * wp2;
        // CONV_ROT = CONV_TRANS = 0.0 : where(err < 0, 0, err) — keep exact semantics
        re = (re < 0.0f) ? 0.0f : re;
        pe = (pe < 0.0f) ? 0.0f : pe;
        cost = 15.0f * re + 100.0f * pe;

        // naturally coalesced scalar outputs
        out[idx] = cost;
        out[(size_t)N + idx] = re;
        out[2 * (size_t)N + idx] = pe;
    }

    // ---- Stage v/omega through LDS so the [N,3] stores are coalesced ----
    __syncthreads();   // all reads of sR done; safe to reuse
    if (active) {
        sR[t * 3 + 0] = v0;
        sR[t * 3 + 1] = v1;
        sR[t * 3 + 2] = v2;
        sR[BLOCK * 3 + t * 3 + 0] = o0;
        sR[BLOCK * 3 + t * 3 + 1] = o1;
        sR[BLOCK * 3 + t * 3 + 2] = o2;
    }
    __syncthreads();

    {
        float* vdst = out + 3 * (size_t)N + (size_t)base * 3;
        float* odst = out + 6 * (size_t)N + (size_t)base * 3;
        if (fullBlock) {
            #pragma unroll
            for (int k = 0; k < 3; ++k) vdst[k * BLOCK + t] = sR[k * BLOCK + t];
            #pragma unroll
            for (int k = 0; k < 3; ++k) odst[k * BLOCK + t] = sR[BLOCK * 3 + k * BLOCK + t];
        } else {
            int rem = N - base;
            #pragma unroll
            for (int k = 0; k < 3; ++k) {
                int i = k * BLOCK + t;
                if (i < rem * 3) { vdst[i] = sR[i]; odst[i] = sR[BLOCK * 3 + i]; }
            }
        }
    }
}

extern "C" void kernel_launch(void* const* d_in, const int* in_sizes, int n_in,
                              void* d_out, int out_size, void* d_ws, size_t ws_size,
                              hipStream_t stream) {
    const float* pos  = (const float*)d_in[0];   // [N,3]
    const float* rot  = (const float*)d_in[1];   // [N,9]
    const float* gpos = (const float*)d_in[2];   // [3]
    const float* grot = (const float*)d_in[3];   // [9]
    const float* wv   = (const float*)d_in[4];   // [6]
    float* out = (float*)d_out;

    const int N = in_sizes[0] / 3;
    const int blocks = (N + BLOCK - 1) / BLOCK;
    hipLaunchKernelGGL(pose_cost_kernel, dim3(blocks), dim3(BLOCK), 0, stream,
                       pos, rot, gpos, grot, wv, out, N);
}